// Round 3
// baseline (159.601 us; speedup 1.0000x reference)
//
#include <hip/hip_runtime.h>
#include <cmath>

#define IMG      512
#define OUTD     502            // 512 - 11 + 1
#define TW       64             // output tile cols per block
#define TH       16             // output tile rows per block
#define NTHREADS 256
#define TILES_X  8              // 8*64 = 512 >= 502
#define TILES_Y  32             // 32*16 = 512 >= 502
#define NIMG     32
#define NBLOCKS  (TILES_X * TILES_Y * NIMG)
#define HT_PITCH 32             // rows per column in H^T planes (ushorts)

typedef float f32x4  __attribute__((ext_vector_type(4)));
typedef short bf16x8 __attribute__((ext_vector_type(8)));

struct WSplit { unsigned short hi[11]; unsigned short lo[11]; };  // bf16 bits

union Frag { unsigned u[4]; bf16x8 v; };

__device__ __forceinline__ unsigned fbits(float x) { return __builtin_bit_cast(unsigned, x); }
__device__ __forceinline__ float truncbf(float x) {
    return __builtin_bit_cast(float, fbits(x) & 0xFFFF0000u);
}
// pack bf16(a) into low 16, bf16(b) into high 16 (truncation)
__device__ __forceinline__ unsigned pkhi(float a, float b) {
    return (fbits(b) & 0xFFFF0000u) | (fbits(a) >> 16);
}
// split 8 fp32 into hi/lo bf16 fragments (element j of frag = value v[j])
__device__ __forceinline__ void split8(const float* v, Frag& fh, Frag& fl) {
    #pragma unroll
    for (int j = 0; j < 4; ++j) {
        const float a = v[2*j], b = v[2*j+1];
        fh.u[j] = pkhi(a, b);
        fl.u[j] = pkhi(a - truncbf(a), b - truncbf(b));
    }
}

#define MFMA16 __builtin_amdgcn_mfma_f32_16x16x32_bf16

// ---------------------------------------------------------------------------
// Fused SSIM via MFMA. Block = 64x16 outputs of one image, 256 threads.
// Stage 1 (horizontal blur): D1 = X[rows][cols] * Wband  -> H (banded matmul,
//   A = raw data rows, k = contiguous cols straight from global).
// Stage 2 (vertical blur):   D2 = H^T[cols][rows] * Wband -> final maps.
// H^T stored in LDS bf16 hi/lo (C-layout lane owns 4 consecutive rows of one
// col -> ds_write_b64). Both stages 3-MFMA hi/lo split: err ~2^-16/pass.
// ---------------------------------------------------------------------------
__global__ __launch_bounds__(NTHREADS, 3)
void ssim_mfma_kernel(const float* __restrict__ ypred,
                      const float* __restrict__ ytrue,
                      float* __restrict__ partials,
                      WSplit ws)
{
    // banded weight matrices Wt[n][k] = w[k-n], n in [0,16), k in [0,32)
    __shared__ unsigned short Wh[16][32], Wl[16][32];           // 2 KB
    // H^T planes: [map*2 + hi/lo][col 0..63][row 0..31] bf16    40 KB
    __shared__ unsigned short Hp[10][TW * HT_PITCH];
    __shared__ float wsum[4];

    const int t    = threadIdx.x;
    const int w    = t >> 6;          // wave 0..3
    const int lane = t & 63;
    const int m16  = lane & 15;
    const int g4   = lane >> 4;       // 0..3

    const int ox0 = blockIdx.x * TW;
    const int oy0 = blockIdx.y * TH;
    const int img = blockIdx.z;

    const size_t imgoff = (size_t)img * (IMG * IMG);
    const float* __restrict__ Xp = ytrue + imgoff;   // X = y_true
    const float* __restrict__ Yp = ypred + imgoff;   // Y = y_pred

    // ---- build banded W (hi/lo) ----
    #pragma unroll
    for (int i = t; i < 512; i += NTHREADS) {
        const int n = i >> 5, k = i & 31, j = k - n;
        const bool in = (j >= 0) && (j <= 10);
        Wh[n][k] = in ? ws.hi[j] : 0;
        Wl[n][k] = in ? ws.lo[j] : 0;
    }
    __syncthreads();

    // B-fragment of W: lane supplies Wt[ n = m16 ][ k = g4*8 + i ]
    Frag wfh, wfl;
    wfh.v = *reinterpret_cast<const bf16x8*>(&Wh[m16][g4 * 8]);
    wfl.v = *reinterpret_cast<const bf16x8*>(&Wl[m16][g4 * 8]);

    // ---------------- Stage 1: horizontal blur via MFMA ----------------
    // 8 units: uid = (rg 0..1) * 4 + (ncg 0..3); wave w does uid = 2w, 2w+1.
    #pragma unroll
    for (int u = 0; u < 2; ++u) {
        const int uid = w * 2 + u;
        const int rg  = uid >> 2;          // row group (16 rows each)
        const int ncg = uid & 3;           // out-col group (16 cols each)

        // A-frag: lane supplies A[ m = m16 ][ k = g4*8 + i ]:
        //   row = oy0 + rg*16 + m16, cols = ox0 + ncg*16 + g4*8 + i
        const int lrow = rg * 16 + m16;
        const int grow = min(oy0 + lrow, IMG - 1);
        const float* __restrict__ Xr = Xp + (size_t)grow * IMG;
        const float* __restrict__ Yr = Yp + (size_t)grow * IMG;
        const int cb = ox0 + ncg * 16 + g4 * 8;

        float xv[8], yv[8];
        #pragma unroll
        for (int j = 0; j < 4; ++j) {
            const int c = min(cb + 2 * j, IMG - 2);      // clamp: only feeds
            const float2 fx = *reinterpret_cast<const float2*>(Xr + c);  // zero-weighted or
            const float2 fy = *reinterpret_cast<const float2*>(Yr + c);  // predicated outputs
            xv[2*j] = fx.x; xv[2*j+1] = fx.y;
            yv[2*j] = fy.x; yv[2*j+1] = fy.y;
        }

        f32x4 acc[5];
        #pragma unroll
        for (int m = 0; m < 5; ++m) acc[m] = (f32x4){0.f, 0.f, 0.f, 0.f};

        float pv[8];
        Frag fh, fl;
        // map 0: X
        split8(xv, fh, fl);
        acc[0] = MFMA16(fh.v, wfh.v, acc[0], 0, 0, 0);
        acc[0] = MFMA16(fl.v, wfh.v, acc[0], 0, 0, 0);
        acc[0] = MFMA16(fh.v, wfl.v, acc[0], 0, 0, 0);
        // map 1: Y
        split8(yv, fh, fl);
        acc[1] = MFMA16(fh.v, wfh.v, acc[1], 0, 0, 0);
        acc[1] = MFMA16(fl.v, wfh.v, acc[1], 0, 0, 0);
        acc[1] = MFMA16(fh.v, wfl.v, acc[1], 0, 0, 0);
        // map 2: X*X
        #pragma unroll
        for (int j = 0; j < 8; ++j) pv[j] = xv[j] * xv[j];
        split8(pv, fh, fl);
        acc[2] = MFMA16(fh.v, wfh.v, acc[2], 0, 0, 0);
        acc[2] = MFMA16(fl.v, wfh.v, acc[2], 0, 0, 0);
        acc[2] = MFMA16(fh.v, wfl.v, acc[2], 0, 0, 0);
        // map 3: Y*Y
        #pragma unroll
        for (int j = 0; j < 8; ++j) pv[j] = yv[j] * yv[j];
        split8(pv, fh, fl);
        acc[3] = MFMA16(fh.v, wfh.v, acc[3], 0, 0, 0);
        acc[3] = MFMA16(fl.v, wfh.v, acc[3], 0, 0, 0);
        acc[3] = MFMA16(fh.v, wfl.v, acc[3], 0, 0, 0);
        // map 4: X*Y
        #pragma unroll
        for (int j = 0; j < 8; ++j) pv[j] = xv[j] * yv[j];
        split8(pv, fh, fl);
        acc[4] = MFMA16(fh.v, wfh.v, acc[4], 0, 0, 0);
        acc[4] = MFMA16(fl.v, wfh.v, acc[4], 0, 0, 0);
        acc[4] = MFMA16(fh.v, wfl.v, acc[4], 0, 0, 0);

        // D1[m][n]: lane holds rows rg*16 + g4*4 + i of out-col ncg*16 + m16.
        // Write transposed into H^T[col][row] (4 consecutive rows = b64),
        // XOR-swizzled by (col&3) to break the 64B-stride bank pattern.
        const int col = ncg * 16 + m16;        // local col 0..63
        const int r0  = rg * 16 + g4 * 4;      // local row base
        #pragma unroll
        for (int m = 0; m < 5; ++m) {
            const float d0 = acc[m][0], d1 = acc[m][1], d2 = acc[m][2], d3 = acc[m][3];
            const unsigned h0 = pkhi(d0, d1), h1 = pkhi(d2, d3);
            const unsigned l0 = pkhi(d0 - truncbf(d0), d1 - truncbf(d1));
            const unsigned l1 = pkhi(d2 - truncbf(d2), d3 - truncbf(d3));
            const unsigned off = col * HT_PITCH + (r0 ^ ((col & 3) << 3));  // ushort units
            *reinterpret_cast<uint2*>(&Hp[m * 2    ][off]) = make_uint2(h0, h1);
            *reinterpret_cast<uint2*>(&Hp[m * 2 + 1][off]) = make_uint2(l0, l1);
        }
    }
    __syncthreads();

    // ---------------- Stage 2: vertical blur via MFMA + SSIM ----------------
    // 4 units, one per wave: col group cg0 = w*16.
    // A-frag: lane supplies A[ m = m16 ][ k = g4*8 + i ] = H^T[cg0+m16][g4*8+i]
    const int cg0  = w * 16;
    const int colL = cg0 + m16;
    const unsigned roff = colL * HT_PITCH + ((g4 * 8) ^ ((colL & 3) << 3));

    f32x4 acc2[5];
    #pragma unroll
    for (int m = 0; m < 5; ++m) {
        Frag ah, al;
        ah.v = *reinterpret_cast<const bf16x8*>(&Hp[m * 2    ][roff]);
        al.v = *reinterpret_cast<const bf16x8*>(&Hp[m * 2 + 1][roff]);
        f32x4 a = (f32x4){0.f, 0.f, 0.f, 0.f};
        a = MFMA16(ah.v, wfh.v, a, 0, 0, 0);
        a = MFMA16(al.v, wfh.v, a, 0, 0, 0);
        a = MFMA16(ah.v, wfl.v, a, 0, 0, 0);
        acc2[m] = a;
    }

    // D2[m][n]: lane holds out cols cg0 + g4*4 + i, out row = m16.
    const float C1 = 0.0001f, C2 = 0.0009f;
    const int orow = oy0 + m16;
    float lsum = 0.f;
    #pragma unroll
    for (int i = 0; i < 4; ++i) {
        const int ocol = ox0 + cg0 + g4 * 4 + i;
        const float mu1 = acc2[0][i], mu2 = acc2[1][i];
        const float s1  = acc2[2][i] - mu1 * mu1;
        const float s2  = acc2[3][i] - mu2 * mu2;
        const float s12 = acc2[4][i] - mu1 * mu2;
        const float num = (2.f * mu1 * mu2 + C1) * (2.f * s12 + C2);
        const float den = (mu1 * mu1 + mu2 * mu2 + C1) * (s1 + s2 + C2);
        const float ssim = num * __builtin_amdgcn_rcpf(den);
        lsum += (ocol < OUTD && orow < OUTD) ? ssim : 0.f;
    }

    // ---------------- block reduction ----------------
    #pragma unroll
    for (int off = 32; off > 0; off >>= 1) lsum += __shfl_down(lsum, off, 64);
    if (lane == 0) wsum[w] = lsum;
    __syncthreads();
    if (t == 0) {
        partials[((size_t)blockIdx.z * TILES_Y + blockIdx.y) * TILES_X + blockIdx.x]
            = wsum[0] + wsum[1] + wsum[2] + wsum[3];
    }
}

// ---------------------------------------------------------------------------
// Final reduction: 8192 partials -> 1 - mean
// ---------------------------------------------------------------------------
__global__ void ssim_reduce_kernel(const float* __restrict__ partials,
                                   float* __restrict__ out)
{
    __shared__ double ws[4];
    const int t = threadIdx.x;
    double s = 0.0;
    for (int i = t; i < NBLOCKS; i += 256) s += (double)partials[i];
    #pragma unroll
    for (int off = 32; off > 0; off >>= 1) s += __shfl_down(s, off, 64);
    if ((t & 63) == 0) ws[t >> 6] = s;
    __syncthreads();
    if (t == 0) {
        const double total = ws[0] + ws[1] + ws[2] + ws[3];
        const double mean  = total / ((double)OUTD * (double)OUTD * (double)NIMG);
        out[0] = (float)(1.0 - mean);
    }
}

static inline unsigned short bf16_rne(float f) {
    unsigned b;
    __builtin_memcpy(&b, &f, 4);
    const unsigned r = b + 0x7FFFu + ((b >> 16) & 1u);
    return (unsigned short)(r >> 16);
}

extern "C" void kernel_launch(void* const* d_in, const int* in_sizes, int n_in,
                              void* d_out, int out_size, void* d_ws, size_t ws_size,
                              hipStream_t stream)
{
    const float* ypred = (const float*)d_in[0];   // y_pred
    const float* ytrue = (const float*)d_in[1];   // y_true
    float* out      = (float*)d_out;
    float* partials = (float*)d_ws;               // NBLOCKS * 4 B = 32 KB

    // Gaussian weights in float64 (matches reference), then exact bf16 hi/lo split.
    double g[11], sum = 0.0;
    for (int i = 0; i < 11; ++i) {
        const double c = (double)i - 5.0;
        g[i] = std::exp(-(c * c) / (2.0 * 1.5 * 1.5));
        sum += g[i];
    }
    WSplit wsp;
    for (int i = 0; i < 11; ++i) {
        const float wf = (float)(g[i] / sum);
        const unsigned short hi = bf16_rne(wf);
        const unsigned hb = ((unsigned)hi) << 16;
        float hif;
        __builtin_memcpy(&hif, &hb, 4);
        wsp.hi[i] = hi;
        wsp.lo[i] = bf16_rne(wf - hif);
    }

    dim3 grid(TILES_X, TILES_Y, NIMG);
    ssim_mfma_kernel<<<grid, NTHREADS, 0, stream>>>(ypred, ytrue, partials, wsp);
    ssim_reduce_kernel<<<1, 256, 0, stream>>>(partials, out);
}

// Round 4
// 116.439 us; speedup vs baseline: 1.3707x; 1.3707x over previous
//
#include <hip/hip_runtime.h>
#include <cmath>

#define IMG      512
#define OUT      502            // 512 - 11 + 1
#define TW       64             // output tile width
#define TH       32             // output tile height
#define IW       74             // input tile width  (TW + 10)
#define PITCH    76             // LDS row pitch in floats (16B-aligned rows)
#define MOFF     (TH * PITCH)   // floats per map = 2432
#define NTHREADS 256
#define TILES_X  8
#define TILES_Y  16
#define NIMG     32
#define NBLOCKS  (TILES_X * TILES_Y * NIMG)

struct GaussW { float w[11]; };

// ---------------------------------------------------------------------------
// Fused SSIM tile kernel. One block = 64x32 outputs of one image.
// 4 blurred maps (not 5): {X, Y, XX+YY, XY} — sigma1_sq+sigma2_sq only ever
// appears summed, and blur is linear, so blur(XX)+blur(YY) = blur(XX+YY).
// Edge tiles are SHIFTED INWARD (no clamped loads -> affine addressing);
// ownership predicate in phase 2 prevents double counting.
// LDS 38.9 KB -> 4 blocks/CU (50% occupancy ceiling).
// ---------------------------------------------------------------------------
__global__ __launch_bounds__(NTHREADS, 4)
void ssim_tile_kernel(const float* __restrict__ ypred,
                      const float* __restrict__ ytrue,
                      float* __restrict__ partials,
                      GaussW gw)
{
    // 4 vertically-blurred maps, flat: [m*MOFF + row*PITCH + col]
    __shared__ __align__(16) float sV[4 * MOFF];
    __shared__ float wsum[4];

    const int t     = threadIdx.x;
    const int tileX = blockIdx.x, tileY = blockIdx.y, img = blockIdx.z;
    // shift last tiles inward so ALL loads are in-bounds (no clamps)
    const int ox0 = (tileX == TILES_X - 1) ? (OUT - TW) : tileX * TW;  // 438 max
    const int oy0 = (tileY == TILES_Y - 1) ? (OUT - TH) : tileY * TH;  // 470 max

    const size_t imgoff = (size_t)img * (IMG * IMG);
    const float* __restrict__ Xp = ytrue + imgoff;   // X = y_true
    const float* __restrict__ Yp = ypred + imgoff;   // Y = y_pred

    // ---------------- Phase 1: vertical blur (global -> regs -> LDS) -------
    // 74 cols x 3 row-groups (11,11,10 outputs) = 222 items, one per thread.
    // Lane -> consecutive column => coalesced global row reads.
    if (t < IW * 3) {
        const int c  = t % IW;
        const int g  = t / IW;
        const int r0 = g * 11;

        // single uint32 offset walk shared by X and Y (SGPR base + VGPR off)
        unsigned off = (unsigned)((oy0 + r0) * IMG + (ox0 + c));

        float acc[4][11];
        #pragma unroll
        for (int m = 0; m < 4; ++m)
            #pragma unroll
            for (int j = 0; j < 11; ++j) acc[m][j] = 0.f;

        // rows r0..r0+19 (all groups); row r0+20 only for g<2 (j=10 tap)
        #pragma unroll
        for (int k = 0; k < 20; ++k) {
            const float x = Xp[off];
            const float y = Yp[off];
            off += IMG;
            const float s = __builtin_fmaf(y, y, x * x);   // XX + YY
            const float p = x * y;                          // XY
            #pragma unroll
            for (int j = 0; j < 11; ++j) {
                if (k - j >= 0 && k - j <= 10) {            // constant-folds per (k,j)
                    const float w = gw.w[k - j];
                    acc[0][j] += w * x;
                    acc[1][j] += w * y;
                    acc[2][j] += w * s;
                    acc[3][j] += w * p;
                }
            }
        }
        if (g < 2) {                                        // k = 20 -> j = 10 only
            const float x = Xp[off];
            const float y = Yp[off];
            const float w = gw.w[10];
            acc[0][10] += w * x;
            acc[1][10] += w * y;
            acc[2][10] += w * __builtin_fmaf(y, y, x * x);
            acc[3][10] += w * (x * y);
        }

        const int o0 = r0 * PITCH + c;
        #pragma unroll
        for (int j = 0; j < 10; ++j) {                      // rows r0..r0+9
            const int o = o0 + j * PITCH;
            sV[0 * MOFF + o] = acc[0][j];
            sV[1 * MOFF + o] = acc[1][j];
            sV[2 * MOFF + o] = acc[2][j];
            sV[3 * MOFF + o] = acc[3][j];
        }
        if (g < 2) {                                        // row r0+10 (j=10)
            const int o = o0 + 10 * PITCH;
            sV[0 * MOFF + o] = acc[0][10];
            sV[1 * MOFF + o] = acc[1][10];
            sV[2 * MOFF + o] = acc[2][10];
            sV[3 * MOFF + o] = acc[3][10];
        }
    }
    __syncthreads();

    // ---------------- Phase 2: horizontal blur + SSIM + reduce -------------
    // Item = (row = t&31, seg = t>>5): 8 output cols per thread.
    // Consecutive 8 lanes span 8 rows -> bank offsets 12*r mod 32 all
    // distinct -> conflict-free ds_read_b128 (R2-measured: 0.72M conflicts).
    const float C1 = 0.0001f;   // (0.01*1)^2
    const float C2 = 0.0009f;   // (0.03*1)^2

    const int row  = t & 31;
    const int seg  = t >> 5;
    const int base = row * PITCH + seg * 8;

    float res[4][8];
    #pragma unroll
    for (int m = 0; m < 4; ++m) {
        const float4 q0 = *reinterpret_cast<const float4*>(&sV[base + m * MOFF +  0]);
        const float4 q1 = *reinterpret_cast<const float4*>(&sV[base + m * MOFF +  4]);
        const float4 q2 = *reinterpret_cast<const float4*>(&sV[base + m * MOFF +  8]);
        const float4 q3 = *reinterpret_cast<const float4*>(&sV[base + m * MOFF + 12]);
        const float4 q4 = *reinterpret_cast<const float4*>(&sV[base + m * MOFF + 16]);
        const float win[20] = { q0.x, q0.y, q0.z, q0.w,
                                q1.x, q1.y, q1.z, q1.w,
                                q2.x, q2.y, q2.z, q2.w,
                                q3.x, q3.y, q3.z, q3.w,
                                q4.x, q4.y, q4.z, q4.w };
        #pragma unroll
        for (int c = 0; c < 8; ++c) {
            float r = 0.f;
            #pragma unroll
            for (int k = 0; k < 11; ++k) r += gw.w[k] * win[c + k];
            res[m][c] = r;
        }
    }

    const int  oy     = oy0 + row;
    const bool rowown = (oy >= tileY * TH);                 // edge-shift ownership
    float lsum = 0.f;

    #pragma unroll
    for (int c = 0; c < 8; ++c) {
        const int  ox  = ox0 + seg * 8 + c;
        const bool own = rowown && (ox >= tileX * TW);
        const float mu1 = res[0][c], mu2 = res[1][c];
        const float b3  = res[2][c];                        // blur(XX+YY)
        const float b4  = res[3][c];                        // blur(XY)
        const float P   = mu1 * mu2;
        const float S   = __builtin_fmaf(mu1, mu1, mu2 * mu2);
        const float num = __builtin_fmaf(2.f, P, C1) * __builtin_fmaf(2.f, b4 - P, C2);
        const float den = (S + C1) * ((b3 + C2) - S);
        const float ssim = num * __builtin_amdgcn_rcpf(den);
        lsum += own ? ssim : 0.f;
    }

    // ---------------- Block reduction ----------------
    #pragma unroll
    for (int off = 32; off > 0; off >>= 1) lsum += __shfl_down(lsum, off, 64);
    if ((t & 63) == 0) wsum[t >> 6] = lsum;
    __syncthreads();
    if (t == 0) {
        const float b = wsum[0] + wsum[1] + wsum[2] + wsum[3];
        partials[((size_t)img * TILES_Y + tileY) * TILES_X + tileX] = b;
    }
}

// ---------------------------------------------------------------------------
// Final reduction: 4096 partials -> 1 - mean
// ---------------------------------------------------------------------------
__global__ void ssim_reduce_kernel(const float* __restrict__ partials,
                                   float* __restrict__ out)
{
    __shared__ double ws[4];
    const int t = threadIdx.x;
    double s = 0.0;
    for (int i = t; i < NBLOCKS; i += 256) s += (double)partials[i];
    #pragma unroll
    for (int off = 32; off > 0; off >>= 1) s += __shfl_down(s, off, 64);
    if ((t & 63) == 0) ws[t >> 6] = s;
    __syncthreads();
    if (t == 0) {
        const double total = ws[0] + ws[1] + ws[2] + ws[3];
        const double mean  = total / ((double)OUT * (double)OUT * (double)NIMG);
        out[0] = (float)(1.0 - mean);
    }
}

extern "C" void kernel_launch(void* const* d_in, const int* in_sizes, int n_in,
                              void* d_out, int out_size, void* d_ws, size_t ws_size,
                              hipStream_t stream)
{
    const float* ypred = (const float*)d_in[0];   // y_pred
    const float* ytrue = (const float*)d_in[1];   // y_true
    float* out      = (float*)d_out;
    float* partials = (float*)d_ws;               // NBLOCKS * 4 B = 16 KB

    // Gaussian weights: float64 math + normalize, then cast — matches reference.
    GaussW gw;
    double g[11], sum = 0.0;
    for (int i = 0; i < 11; ++i) {
        const double c = (double)i - 5.0;
        g[i] = std::exp(-(c * c) / (2.0 * 1.5 * 1.5));
        sum += g[i];
    }
    for (int i = 0; i < 11; ++i) gw.w[i] = (float)(g[i] / sum);

    dim3 grid(TILES_X, TILES_Y, NIMG);
    ssim_tile_kernel<<<grid, NTHREADS, 0, stream>>>(ypred, ytrue, partials, gw);
    ssim_reduce_kernel<<<1, 256, 0, stream>>>(partials, out);
}

// Round 5
// 116.118 us; speedup vs baseline: 1.3745x; 1.0028x over previous
//
#include <hip/hip_runtime.h>
#include <cmath>

#define IMG      512
#define OUT      502            // 512 - 11 + 1
#define TW       64             // output tile width
#define TH       32             // output tile height
#define IW       74             // input tile width  (TW + 10)
#define P2       78             // LDS row pitch in float2 units (even -> 16B rows)
#define NTHREADS 256
#define TILES_X  8
#define TILES_Y  16
#define NIMG     32
#define NBLOCKS  (TILES_X * TILES_Y * NIMG)

struct GaussW { float w[11]; };

// ---------------------------------------------------------------------------
// Fused SSIM tile kernel. One block = 64x32 outputs of one image.
// 4 blurred maps {X, Y, XX+YY, XY} stored as 2 float2-interleaved LDS planes.
// Phase 1 loads its 21 rows into register arrays UP FRONT (independent loads,
// one latency exposure) -- R4's `off += IMG` walk was a 20-deep dependent
// load chain and latency-bound at VGPR=68.
// Edge tiles shifted inward; ownership predicate prevents double counting.
// LDS 39.9 KB -> 4 blocks/CU.
// ---------------------------------------------------------------------------
__global__ __launch_bounds__(NTHREADS, 4)
void ssim_tile_kernel(const float* __restrict__ ypred,
                      const float* __restrict__ ytrue,
                      float* __restrict__ partials,
                      GaussW gw)
{
    __shared__ __align__(16) float2 sXY[TH * P2];   // (vblur X, vblur Y)
    __shared__ __align__(16) float2 sSP[TH * P2];   // (vblur XX+YY, vblur XY)
    __shared__ float wsum[4];

    const int t     = threadIdx.x;
    const int tileX = blockIdx.x, tileY = blockIdx.y, img = blockIdx.z;
    // shift last tiles inward so ALL loads are in-bounds (no clamps)
    const int ox0 = (tileX == TILES_X - 1) ? (OUT - TW) : tileX * TW;  // <=438
    const int oy0 = (tileY == TILES_Y - 1) ? (OUT - TH) : tileY * TH;  // <=470

    const size_t imgoff = (size_t)img * (IMG * IMG);
    const float* __restrict__ Xp = ytrue + imgoff;   // X = y_true
    const float* __restrict__ Yp = ypred + imgoff;   // Y = y_pred

    // ---------------- Phase 1: vertical blur (global -> regs -> LDS) -------
    // 74 cols x 3 row-groups (11,11,10 outputs) = 222 items, one per thread.
    if (t < IW * 3) {
        const int c  = t % IW;
        const int g  = t / IW;
        const int r0 = g * 11;

        const unsigned off0 = (unsigned)((oy0 + r0) * IMG + (ox0 + c));

        // batched independent loads: all 21 rows into registers first
        float xv[21], yv[21];
        #pragma unroll
        for (int k = 0; k < 20; ++k) {
            xv[k] = Xp[off0 + k * IMG];
            yv[k] = Yp[off0 + k * IMG];
        }
        {   // row 20 would be OOB for g==2 (never used there): load row 0 instead
            const unsigned o20 = (g < 2) ? (off0 + 20 * IMG) : off0;
            xv[20] = Xp[o20];
            yv[20] = Yp[o20];
        }

        float aX[11], aY[11], aS[11], aP[11];
        #pragma unroll
        for (int j = 0; j < 11; ++j) { aX[j] = 0.f; aY[j] = 0.f; aS[j] = 0.f; aP[j] = 0.f; }

        #pragma unroll
        for (int k = 0; k < 20; ++k) {
            const float x = xv[k];
            const float y = yv[k];
            const float s = __builtin_fmaf(y, y, x * x);   // XX + YY
            const float p = x * y;                          // XY
            #pragma unroll
            for (int j = 0; j < 11; ++j) {
                if (k - j >= 0 && k - j <= 10) {            // constant-folds per (k,j)
                    const float w = gw.w[k - j];
                    aX[j] += w * x;
                    aY[j] += w * y;
                    aS[j] += w * s;
                    aP[j] += w * p;
                }
            }
        }
        if (g < 2) {                                        // k = 20 -> j = 10 only
            const float x = xv[20];
            const float y = yv[20];
            const float w = gw.w[10];
            aX[10] += w * x;
            aY[10] += w * y;
            aS[10] += w * __builtin_fmaf(y, y, x * x);
            aP[10] += w * (x * y);
        }

        const int o0 = r0 * P2 + c;
        #pragma unroll
        for (int j = 0; j < 10; ++j) {                      // rows r0..r0+9
            const int o = o0 + j * P2;
            sXY[o] = make_float2(aX[j], aY[j]);             // ds_write_b64
            sSP[o] = make_float2(aS[j], aP[j]);
        }
        if (g < 2) {                                        // row r0+10 (j=10)
            const int o = o0 + 10 * P2;
            sXY[o] = make_float2(aX[10], aY[10]);
            sSP[o] = make_float2(aS[10], aP[10]);
        }
    }
    __syncthreads();

    // ---------------- Phase 2: horizontal blur + SSIM + reduce -------------
    // Item = (row = t&31, seg = t>>5): 8 output cols per thread.
    // 9 ds_read_b128 per plane cover float2 cols seg*8 .. seg*8+17.
    // Bank check (pitch 78 f2 = 156 dwords, 156%32=28): b128 start banks
    // partition into multiples of 4 -> uniform 4 lanes/bank = inherent, no
    // excess conflict. Row byte offset even*8 -> 16B aligned float4 reads.
    const float C1 = 0.0001f;   // (0.01*1)^2
    const float C2 = 0.0009f;   // (0.03*1)^2

    const int row  = t & 31;
    const int seg  = t >> 5;
    const int base = row * P2 + seg * 8;

    float winA[18], winB[18];

    // ---- plane 1: (X, Y) ----
    {
        const float4* q = reinterpret_cast<const float4*>(&sXY[base]);
        #pragma unroll
        for (int i = 0; i < 9; ++i) {
            const float4 v = q[i];
            winA[2*i]     = v.x;  winB[2*i]     = v.y;
            winA[2*i + 1] = v.z;  winB[2*i + 1] = v.w;
        }
    }
    float mu1v[8], mu2v[8];
    #pragma unroll
    for (int c = 0; c < 8; ++c) {
        float r1 = 0.f, r2 = 0.f;
        #pragma unroll
        for (int k = 0; k < 11; ++k) {
            const float w = gw.w[k];
            r1 += w * winA[c + k];
            r2 += w * winB[c + k];
        }
        mu1v[c] = r1; mu2v[c] = r2;
    }

    // ---- plane 2: (XX+YY, XY) ----
    {
        const float4* q = reinterpret_cast<const float4*>(&sSP[base]);
        #pragma unroll
        for (int i = 0; i < 9; ++i) {
            const float4 v = q[i];
            winA[2*i]     = v.x;  winB[2*i]     = v.y;
            winA[2*i + 1] = v.z;  winB[2*i + 1] = v.w;
        }
    }

    const int  oy     = oy0 + row;
    const bool rowown = (oy >= tileY * TH);                 // edge-shift ownership
    float lsum = 0.f;

    #pragma unroll
    for (int c = 0; c < 8; ++c) {
        float b3 = 0.f, b4 = 0.f;
        #pragma unroll
        for (int k = 0; k < 11; ++k) {
            const float w = gw.w[k];
            b3 += w * winA[c + k];                          // blur(XX+YY)
            b4 += w * winB[c + k];                          // blur(XY)
        }
        const int  ox  = ox0 + seg * 8 + c;
        const bool own = rowown && (ox >= tileX * TW);
        const float mu1 = mu1v[c], mu2 = mu2v[c];
        const float Pm  = mu1 * mu2;
        const float Sm  = __builtin_fmaf(mu1, mu1, mu2 * mu2);
        const float num = __builtin_fmaf(2.f, Pm, C1) * __builtin_fmaf(2.f, b4 - Pm, C2);
        const float den = (Sm + C1) * ((b3 + C2) - Sm);
        const float ssim = num * __builtin_amdgcn_rcpf(den);
        lsum += own ? ssim : 0.f;
    }

    // ---------------- Block reduction ----------------
    #pragma unroll
    for (int off = 32; off > 0; off >>= 1) lsum += __shfl_down(lsum, off, 64);
    if ((t & 63) == 0) wsum[t >> 6] = lsum;
    __syncthreads();
    if (t == 0) {
        const float b = wsum[0] + wsum[1] + wsum[2] + wsum[3];
        partials[((size_t)img * TILES_Y + tileY) * TILES_X + tileX] = b;
    }
}

// ---------------------------------------------------------------------------
// Final reduction: 4096 partials -> 1 - mean
// ---------------------------------------------------------------------------
__global__ void ssim_reduce_kernel(const float* __restrict__ partials,
                                   float* __restrict__ out)
{
    __shared__ double ws[4];
    const int t = threadIdx.x;
    double s = 0.0;
    for (int i = t; i < NBLOCKS; i += 256) s += (double)partials[i];
    #pragma unroll
    for (int off = 32; off > 0; off >>= 1) s += __shfl_down(s, off, 64);
    if ((t & 63) == 0) ws[t >> 6] = s;
    __syncthreads();
    if (t == 0) {
        const double total = ws[0] + ws[1] + ws[2] + ws[3];
        const double mean  = total / ((double)OUT * (double)OUT * (double)NIMG);
        out[0] = (float)(1.0 - mean);
    }
}

extern "C" void kernel_launch(void* const* d_in, const int* in_sizes, int n_in,
                              void* d_out, int out_size, void* d_ws, size_t ws_size,
                              hipStream_t stream)
{
    const float* ypred = (const float*)d_in[0];   // y_pred
    const float* ytrue = (const float*)d_in[1];   // y_true
    float* out      = (float*)d_out;
    float* partials = (float*)d_ws;               // NBLOCKS * 4 B = 16 KB

    // Gaussian weights: float64 math + normalize, then cast — matches reference.
    GaussW gw;
    double g[11], sum = 0.0;
    for (int i = 0; i < 11; ++i) {
        const double c = (double)i - 5.0;
        g[i] = std::exp(-(c * c) / (2.0 * 1.5 * 1.5));
        sum += g[i];
    }
    for (int i = 0; i < 11; ++i) gw.w[i] = (float)(g[i] / sum);

    dim3 grid(TILES_X, TILES_Y, NIMG);
    ssim_tile_kernel<<<grid, NTHREADS, 0, stream>>>(ypred, ytrue, partials, gw);
    ssim_reduce_kernel<<<1, 256, 0, stream>>>(partials, out);
}